// Round 5
// baseline (767.266 us; speedup 1.0000x reference)
//
#include <hip/hip_runtime.h>
#include <math.h>

#define BATCH    65536
#define HID      128
#define SELF_DIM 18
#define NBR_DIM  6
#define OBS_W    66
#define RB       64      // rows per block
#define NTHREADS 512     // 8 waves x 16 cols each
#define X0S      32      // pow2 LDS stride for the 24-wide input (zero-padded)

using bf16x8 = __attribute__((ext_vector_type(8))) short;
using f32x4  = __attribute__((ext_vector_type(4))) float;

// ---- ws layout (element offsets into a short*) ----
#define E1H 0            // eW1^T hi  [128][32]
#define E1L 4096
#define E2H 8192         // eW2^T hi  [128][128]
#define E2L 24576
#define V1H 40960
#define V1L 57344
#define V2H 73728
#define V2L 90112
#define A1H 106496       // aW1^T hi  [128][256]
#define A1L 139264
#define A2H 172032
#define A2L 188416
#define MEANH 204800     // mean hi   [BATCH][128]
#define MEANL (MEANH + BATCH*HID)
#define WS_ELEMS_FULL (MEANL + BATCH*HID)

__device__ __forceinline__ float4 ld4(const float* p) { return *reinterpret_cast<const float4*>(p); }

// packed RNE bf16 pair: low16 = bf16(a), high16 = bf16(b)
__device__ __forceinline__ unsigned cvtpk(float a, float b) {
    unsigned r;
    asm("v_cvt_pk_bf16_f32 %0, %1, %2" : "=v"(r) : "v"(a), "v"(b));
    return r;
}

// tanh = 1 - 2/(2^(2*log2e*x)+1); inf-safe at both ends
__device__ __forceinline__ float tanh_f(float x) {
    float t = __builtin_amdgcn_exp2f(x * 2.8853900817779268f);
    float r = __builtin_amdgcn_rcpf(t + 1.f);
    return 1.f - 2.f * r;
}

__device__ __forceinline__ f32x4 mfma16(bf16x8 a, bf16x8 b, f32x4 c) {
    return __builtin_amdgcn_mfma_f32_16x16x32_bf16(a, b, c, 0, 0, 0);
}
__device__ __forceinline__ void zacc(f32x4 acc[4]) {
    #pragma unroll
    for (int rt = 0; rt < 4; ++rt) acc[rt] = f32x4{0.f, 0.f, 0.f, 0.f};
}

// All-T matmul, wave owns 16 cols. A-frag = W^T (global, per-lane ptr + imm),
// B-frag = X (LDS, per-lane even/odd-ks ptrs + imm). 3-term hi/lo split, term-major.
template<int NKS, int RTS>   // RTS: rt element stride in X (2048 for HID bufs, 512 for X0)
__device__ __forceinline__ void mmT(f32x4 acc[4],
        const short* xhE, const short* xhO, const short* xlE, const short* xlO,
        const short* __restrict__ whp, const short* __restrict__ wlp)
{
    #pragma unroll
    for (int ks = 0; ks < NKS; ++ks) {
        const short* xh = (ks & 1) ? xhO : xhE;
        const short* xl = (ks & 1) ? xlO : xlE;
        bf16x8 wh = *(const bf16x8*)(whp + ks * 32);
        bf16x8 wl = *(const bf16x8*)(wlp + ks * 32);
        bf16x8 ah[4], al[4];
        #pragma unroll
        for (int rt = 0; rt < 4; ++rt) {
            ah[rt] = *(const bf16x8*)(xh + ks * 32 + rt * RTS);
            al[rt] = *(const bf16x8*)(xl + ks * 32 + rt * RTS);
        }
        __builtin_amdgcn_s_setprio(1);
        #pragma unroll
        for (int rt = 0; rt < 4; ++rt) acc[rt] = mfma16(wh, ah[rt], acc[rt]);
        #pragma unroll
        for (int rt = 0; rt < 4; ++rt) acc[rt] = mfma16(wh, al[rt], acc[rt]);
        #pragma unroll
        for (int rt = 0; rt < 4; ++rt) acc[rt] = mfma16(wl, ah[rt], acc[rt]);
        __builtin_amdgcn_s_setprio(0);
    }
}

// tanh(acc + bias) -> hi/lo split (cvt_pk) -> b64 stores at stoff + rt*2048
__device__ __forceinline__ void epi_tanh_store(f32x4 acc[4], const float* __restrict__ bias,
        short* Xh, short* Xl, int j0, int stoff)
{
    float4 bb = ld4(&bias[j0]);
    #pragma unroll
    for (int rt = 0; rt < 4; ++rt) {
        float v0 = tanh_f(acc[rt][0] + bb.x);
        float v1 = tanh_f(acc[rt][1] + bb.y);
        float v2 = tanh_f(acc[rt][2] + bb.z);
        float v3 = tanh_f(acc[rt][3] + bb.w);
        unsigned h01 = cvtpk(v0, v1), h23 = cvtpk(v2, v3);
        float f0 = __uint_as_float(h01 << 16), f1 = __uint_as_float(h01 & 0xffff0000u);
        float f2 = __uint_as_float(h23 << 16), f3 = __uint_as_float(h23 & 0xffff0000u);
        unsigned l01 = cvtpk(v0 - f0, v1 - f1), l23 = cvtpk(v2 - f2, v3 - f3);
        *reinterpret_cast<uint2*>(Xh + stoff + rt * 2048) = make_uint2(h01, h23);
        *reinterpret_cast<uint2*>(Xl + stoff + rt * 2048) = make_uint2(l01, l23);
    }
}

// build X0 rows: [self_obs[r % B] | obs[r/8] nbr slice | zeros], split hi/lo
__device__ __forceinline__ void build_x0(short* X0h, short* X0l,
        const float* __restrict__ self_obs, const float* __restrict__ obs,
        int r0, int tid)
{
    for (int idx = tid; idx < RB * X0S; idx += NTHREADS) {
        int s = idx >> 5, c = idx & 31;
        int r = r0 + s;
        float v = 0.f;
        if (c < SELF_DIM) v = self_obs[(size_t)(r & (BATCH - 1)) * SELF_DIM + c];
        else if (c < 24)  v = obs[(size_t)(r >> 3) * OBS_W + SELF_DIM + (r & 7) * NBR_DIM + (c - SELF_DIM)];
        unsigned u = __float_as_uint(v);
        unsigned h = (u + 0x7fffu + ((u >> 16) & 1u)) >> 16;
        float lf = v - __uint_as_float(h << 16);
        X0h[idx] = (short)h;
        X0l[idx] = (short)(__float_as_uint(lf) >> 16);
    }
}

// ================= prep: W -> W^T bf16 hi/lo in ws =================
__global__ void prep_w(const float* __restrict__ eW1, const float* __restrict__ eW2,
                       const float* __restrict__ vW1, const float* __restrict__ vW2,
                       const float* __restrict__ aW1, const float* __restrict__ aW2,
                       short* __restrict__ ws)
{
    int t = blockIdx.x * blockDim.x + threadIdx.x;
    float v; int dh, dl;
    if (t < 4096)        { int u = t;          int c = u >> 5, k = u & 31;
                           v = (k < 24) ? eW1[k * HID + c] : 0.f; dh = E1H + u; dl = E1L + u; }
    else if (t < 20480)  { int u = t - 4096;   int c = u >> 7, k = u & 127;
                           v = eW2[k * HID + c]; dh = E2H + u; dl = E2L + u; }
    else if (t < 36864)  { int u = t - 20480;  int c = u >> 7, k = u & 127;
                           v = vW1[k * HID + c]; dh = V1H + u; dl = V1L + u; }
    else if (t < 53248)  { int u = t - 36864;  int c = u >> 7, k = u & 127;
                           v = vW2[k * HID + c]; dh = V2H + u; dl = V2L + u; }
    else if (t < 86016)  { int u = t - 53248;  int c = u >> 8, k = u & 255;
                           v = aW1[k * HID + c]; dh = A1H + u; dl = A1L + u; }
    else if (t < 102400) { int u = t - 86016;  int c = u >> 7, k = u & 127;
                           v = aW2[k * HID + c]; dh = A2H + u; dl = A2L + u; }
    else return;
    unsigned uu = __float_as_uint(v);
    unsigned h = (uu + 0x7fffu + ((uu >> 16) & 1u)) >> 16;
    float lf = v - __uint_as_float(h << 16);
    ws[dh] = (short)h;
    ws[dl] = (short)(__float_as_uint(lf) >> 16);
}

// bijective remap: hw-adjacent 8-groups = logical blocks stride 1024 (share self/mean rows)
__device__ __forceinline__ int remap_bid(int b) { return ((b & 7) << 10) | (b >> 3); }

// ================= kernel A: emb -> group means (bf16 hi/lo to ws) =================
__global__ __launch_bounds__(NTHREADS, 4)
void qk_mean(const float* __restrict__ self_obs, const float* __restrict__ obs,
             const float* __restrict__ eb1, const float* __restrict__ eb2,
             short* __restrict__ ws, int use_ml)
{
    __shared__ __align__(16) short X0h[RB * X0S], X0l[RB * X0S];
    __shared__ __align__(16) short XPh[RB * HID], XPl[RB * HID];

    const int tid = threadIdx.x, lane = tid & 63, w = tid >> 6;
    const int lm = lane & 15, q = lane >> 4, q8 = q << 3;
    const int swz = (lm & 7) << 3;
    const int swz_lo = swz & 0x18, swz_hi = swz & 0x20;
    const int xboff = lm * HID + (q8 ^ swz_lo);
    const int xbE = xboff + swz_hi, xbO = xboff - swz_hi;
    const int j0 = (w << 4) + (q << 2);
    const int stoff = lm * HID + (j0 ^ swz);
    const int x0off = lm * X0S + q8;
    const int bidx = remap_bid(blockIdx.x);
    const int r0 = bidx * RB;

    build_x0(X0h, X0l, self_obs, obs, r0, tid);
    __syncthreads();

    f32x4 acc[4];
    // L1 (K=32, X0 unswizzled)
    zacc(acc);
    {
        const int c0 = (w << 4) + lm;
        mmT<1, 512>(acc, X0h + x0off, X0h + x0off, X0l + x0off, X0l + x0off,
                    ws + E1H + c0 * 32 + q8, ws + E1L + c0 * 32 + q8);
    }
    epi_tanh_store(acc, eb1, XPh, XPl, j0, stoff);
    __syncthreads();

    // L2 -> emb, group means in-register
    zacc(acc);
    {
        const int c0 = (w << 4) + lm;
        mmT<4, 2048>(acc, XPh + xbE, XPh + xbO, XPl + xbE, XPl + xbO,
                     ws + E2H + c0 * 128 + q8, ws + E2L + c0 * 128 + q8);
    }
    {
        short* mh  = ws + MEANH;
        short* mlp = ws + MEANL;
        float4 bb = ld4(&eb2[j0]);
        #pragma unroll
        for (int rt = 0; rt < 4; ++rt) {
            float v0 = tanh_f(acc[rt][0] + bb.x);
            float v1 = tanh_f(acc[rt][1] + bb.y);
            float v2 = tanh_f(acc[rt][2] + bb.z);
            float v3 = tanh_f(acc[rt][3] + bb.w);
            #pragma unroll
            for (int m = 1; m <= 4; m <<= 1) {
                v0 += __shfl_xor(v0, m); v1 += __shfl_xor(v1, m);
                v2 += __shfl_xor(v2, m); v3 += __shfl_xor(v3, m);
            }
            if ((lm & 7) == 0) {
                v0 *= 0.125f; v1 *= 0.125f; v2 *= 0.125f; v3 *= 0.125f;
                unsigned h01 = cvtpk(v0, v1), h23 = cvtpk(v2, v3);
                size_t g = (size_t)bidx * 8 + rt * 2 + (lm >> 3);
                *reinterpret_cast<uint2*>(mh + g * HID + j0) = make_uint2(h01, h23);
                if (use_ml) {
                    float f0 = __uint_as_float(h01 << 16), f1 = __uint_as_float(h01 & 0xffff0000u);
                    float f2 = __uint_as_float(h23 << 16), f3 = __uint_as_float(h23 & 0xffff0000u);
                    unsigned l01 = cvtpk(v0 - f0, v1 - f1), l23 = cvtpk(v2 - f2, v3 - f3);
                    *reinterpret_cast<uint2*>(mlp + g * HID + j0) = make_uint2(l01, l23);
                }
            }
        }
    }
}

// ================= kernel B: full pipeline =================
__global__ __launch_bounds__(NTHREADS, 4)
void qk_main(const float* __restrict__ self_obs, const float* __restrict__ obs,
             const float* __restrict__ eb1, const float* __restrict__ eb2,
             const float* __restrict__ vb1, const float* __restrict__ vb2,
             const float* __restrict__ ab1, const float* __restrict__ ab2,
             const float* __restrict__ aW3,
             const short* __restrict__ ws, float* __restrict__ out, int use_ml)
{
    __shared__ __align__(16) short X0h[RB * X0S], X0l[RB * X0S];   // 8 KB
    __shared__ __align__(16) short XPh[RB * HID], XPl[RB * HID];   // 32 KB
    __shared__ __align__(16) short Eh[RB * HID],  El[RB * HID];    // 32 KB
    __shared__ float spart[8][RB];                                  // 2 KB
    __shared__ float attnb[RB];

    const int tid = threadIdx.x, lane = tid & 63, w = tid >> 6;
    const int lm = lane & 15, q = lane >> 4, q8 = q << 3;
    const int swz = (lm & 7) << 3;
    const int swz_lo = swz & 0x18, swz_hi = swz & 0x20;
    const int xboff = lm * HID + (q8 ^ swz_lo);
    const int xbE = xboff + swz_hi, xbO = xboff - swz_hi;
    const int j0 = (w << 4) + (q << 2);
    const int stoff = lm * HID + (j0 ^ swz);
    const int x0off = lm * X0S + q8;
    const int c0 = (w << 4) + lm;
    const int bidx = remap_bid(blockIdx.x);
    const int r0 = bidx * RB;

    build_x0(X0h, X0l, self_obs, obs, r0, tid);
    __syncthreads();

    f32x4 acc[4];

    // ---- L1: tanh(X0 @ eW1 + eb1) -> XP
    zacc(acc);
    mmT<1, 512>(acc, X0h + x0off, X0h + x0off, X0l + x0off, X0l + x0off,
                ws + E1H + c0 * 32 + q8, ws + E1L + c0 * 32 + q8);
    epi_tanh_store(acc, eb1, XPh, XPl, j0, stoff);
    __syncthreads();

    // ---- L2: tanh(XP @ eW2 + eb2) -> E (emb)
    zacc(acc);
    mmT<4, 2048>(acc, XPh + xbE, XPh + xbO, XPl + xbE, XPl + xbO,
                 ws + E2H + c0 * 128 + q8, ws + E2L + c0 * 128 + q8);
    epi_tanh_store(acc, eb2, Eh, El, j0, stoff);
    __syncthreads();

    // ---- L5: tanh([emb | mean] @ aW1 + ab1) -> XP
    zacc(acc);
    mmT<4, 2048>(acc, Eh + xbE, Eh + xbO, El + xbE, El + xbO,
                 ws + A1H + c0 * 256 + q8, ws + A1L + c0 * 256 + q8);
    {   // mean half: B-frags from global means (row = (r0+r) % B, contiguous in-block)
        const size_t mbase = (size_t)(r0 & (BATCH - 1)) * HID + lm * HID + q8;
        const short* __restrict__ mhp = ws + MEANH + mbase;
        const short* __restrict__ mlp = ws + MEANL + mbase;
        const short* __restrict__ whp = ws + A1H + c0 * 256 + 128 + q8;
        const short* __restrict__ wlp = ws + A1L + c0 * 256 + 128 + q8;
        #pragma unroll
        for (int ks = 0; ks < 4; ++ks) {
            bf16x8 wh = *(const bf16x8*)(whp + ks * 32);
            bf16x8 wl = *(const bf16x8*)(wlp + ks * 32);
            bf16x8 mhf[4], mlf[4];
            #pragma unroll
            for (int rt = 0; rt < 4; ++rt) {
                mhf[rt] = *(const bf16x8*)(mhp + ks * 32 + rt * 2048);
                if (use_ml) mlf[rt] = *(const bf16x8*)(mlp + ks * 32 + rt * 2048);
            }
            __builtin_amdgcn_s_setprio(1);
            #pragma unroll
            for (int rt = 0; rt < 4; ++rt) acc[rt] = mfma16(wh, mhf[rt], acc[rt]);
            #pragma unroll
            for (int rt = 0; rt < 4; ++rt) acc[rt] = mfma16(wl, mhf[rt], acc[rt]);
            if (use_ml) {
                #pragma unroll
                for (int rt = 0; rt < 4; ++rt) acc[rt] = mfma16(wh, mlf[rt], acc[rt]);
            }
            __builtin_amdgcn_s_setprio(0);
        }
    }
    epi_tanh_store(acc, ab1, XPh, XPl, j0, stoff);
    __syncthreads();

    // ---- L6: h2 = tanh(XP @ aW2 + ab2); per-wave score partials (ab3 cancels in softmax)
    zacc(acc);
    mmT<4, 2048>(acc, XPh + xbE, XPh + xbO, XPl + xbE, XPl + xbO,
                 ws + A2H + c0 * 128 + q8, ws + A2L + c0 * 128 + q8);
    {
        float4 bb = ld4(&ab2[j0]);
        float4 w3 = ld4(&aW3[j0]);
        #pragma unroll
        for (int rt = 0; rt < 4; ++rt) {
            float p = tanh_f(acc[rt][0] + bb.x) * w3.x
                    + tanh_f(acc[rt][1] + bb.y) * w3.y
                    + tanh_f(acc[rt][2] + bb.z) * w3.z
                    + tanh_f(acc[rt][3] + bb.w) * w3.w;
            p += __shfl_xor(p, 16);
            p += __shfl_xor(p, 32);
            if (q == 0) spart[w][rt * 16 + lm] = p;
        }
    }
    __syncthreads();

    // ---- L3: tanh(E @ vW1 + vb1) -> XP;  wave 0 lanes 0-7: scores -> softmax -> attnb
    if (w == 0 && lane < 8) {
        const int g = lane;
        float sc[8];
        #pragma unroll
        for (int k = 0; k < 8; ++k) {
            float s = 0.f;
            #pragma unroll
            for (int ww = 0; ww < 8; ++ww) s += spart[ww][g * 8 + k];
            sc[k] = s;
        }
        float mx = -1e30f;
        #pragma unroll
        for (int k = 0; k < 8; ++k) mx = fmaxf(mx, sc[k]);
        float es[8], ssum = 0.f;
        #pragma unroll
        for (int k = 0; k < 8; ++k) { es[k] = __expf(sc[k] - mx); ssum += es[k]; }
        float inv = __builtin_amdgcn_rcpf(ssum);
        #pragma unroll
        for (int k = 0; k < 8; ++k) attnb[g * 8 + k] = es[k] * inv;
    }
    zacc(acc);
    mmT<4, 2048>(acc, Eh + xbE, Eh + xbO, El + xbE, El + xbO,
                 ws + V1H + c0 * 128 + q8, ws + V1L + c0 * 128 + q8);
    epi_tanh_store(acc, vb1, XPh, XPl, j0, stoff);
    __syncthreads();

    // ---- L4: vals = tanh(XP @ vW2 + vb2); out = sum_group attn * vals
    zacc(acc);
    mmT<4, 2048>(acc, XPh + xbE, XPh + xbO, XPl + xbE, XPl + xbO,
                 ws + V2H + c0 * 128 + q8, ws + V2L + c0 * 128 + q8);
    {
        float4 bb = ld4(&vb2[j0]);
        #pragma unroll
        for (int rt = 0; rt < 4; ++rt) {
            float a = attnb[rt * 16 + lm];
            float s0 = a * tanh_f(acc[rt][0] + bb.x);
            float s1 = a * tanh_f(acc[rt][1] + bb.y);
            float s2 = a * tanh_f(acc[rt][2] + bb.z);
            float s3 = a * tanh_f(acc[rt][3] + bb.w);
            #pragma unroll
            for (int m = 1; m <= 4; m <<= 1) {
                s0 += __shfl_xor(s0, m); s1 += __shfl_xor(s1, m);
                s2 += __shfl_xor(s2, m); s3 += __shfl_xor(s3, m);
            }
            if ((lm & 7) == 0) {
                size_t b = (size_t)bidx * 8 + rt * 2 + (lm >> 3);
                *reinterpret_cast<float4*>(&out[b * HID + j0]) = make_float4(s0, s1, s2, s3);
            }
        }
    }
}

extern "C" void kernel_launch(void* const* d_in, const int* in_sizes, int n_in,
                              void* d_out, int out_size, void* d_ws, size_t ws_size,
                              hipStream_t stream) {
    const float* self_obs = (const float*)d_in[0];
    const float* obs      = (const float*)d_in[1];
    const float* eW1 = (const float*)d_in[2];  const float* eb1 = (const float*)d_in[3];
    const float* eW2 = (const float*)d_in[4];  const float* eb2 = (const float*)d_in[5];
    const float* vW1 = (const float*)d_in[6];  const float* vb1 = (const float*)d_in[7];
    const float* vW2 = (const float*)d_in[8];  const float* vb2 = (const float*)d_in[9];
    const float* aW1 = (const float*)d_in[10]; const float* ab1 = (const float*)d_in[11];
    const float* aW2 = (const float*)d_in[12]; const float* ab2 = (const float*)d_in[13];
    const float* aW3 = (const float*)d_in[14];
    float* out = (float*)d_out;
    short* ws = (short*)d_ws;

    int use_ml = (ws_size >= (size_t)WS_ELEMS_FULL * sizeof(short)) ? 1 : 0;

    prep_w<<<400, 256, 0, stream>>>(eW1, eW2, vW1, vW2, aW1, aW2, ws);

    dim3 grid(BATCH * 8 / RB);   // 8192
    qk_mean<<<grid, NTHREADS, 0, stream>>>(self_obs, obs, eb1, eb2, ws, use_ml);
    qk_main<<<grid, NTHREADS, 0, stream>>>(self_obs, obs, eb1, eb2, vb1, vb2,
                                           ab1, ab2, aW3, ws, out, use_ml);
}